// Round 2
// baseline (123.758 us; speedup 1.0000x reference)
//
#include <hip/hip_runtime.h>
#include <stdint.h>

typedef __attribute__((ext_vector_type(8))) __bf16 bf16x8;
typedef __attribute__((ext_vector_type(4))) float f32x4;

__device__ __forceinline__ unsigned short f2bf(float f) {
  union { float f; unsigned int u; } v; v.f = f;
  unsigned int u = v.u;
  u = (u + 0x7FFFu + ((u >> 16) & 1u)) >> 16;   // RNE
  return (unsigned short)u;
}

// ---------------------------------------------------------------------------
// Kernel 1: causal Gaussian filter along t (16 taps; tap>=16 is <1.3e-14),
// emits filtered as bf16. Grid: B * (S/TS) blocks, 256 thr.
// Each thread owns one float4 column (d4) and a strip of TS=8 t-values.
// ---------------------------------------------------------------------------
constexpr int KW = 16;
constexpr int TS = 8;

__global__ __launch_bounds__(256) void filter_conv(
    const float* __restrict__ x, unsigned short* __restrict__ fb)
{
  const int d4 = threadIdx.x;                 // 0..255
  const int strip = blockIdx.x;               // b*128 + ts
  const int b = strip >> 7;
  const int t0 = (strip & 127) * TS;
  const size_t rb = (size_t)b * 1024;         // row base = b*S

  float g[KW];
#pragma unroll
  for (int k = 0; k < KW; ++k) g[k] = __expf(-(float)(k * k) * 0.125f);

  float4 acc[TS];
#pragma unroll
  for (int u = 0; u < TS; ++u) acc[u] = make_float4(0.f, 0.f, 0.f, 0.f);

#pragma unroll
  for (int dt = 0; dt < TS + KW - 1; ++dt) {  // 23 input rows
    const int j = t0 - (KW - 1) + dt;
    float4 xj = make_float4(0.f, 0.f, 0.f, 0.f);
    if (j >= 0) xj = *(const float4*)(x + (rb + j) * 1024 + d4 * 4);
#pragma unroll
    for (int u = 0; u < TS; ++u) {
      const int k = u + (KW - 1) - dt;        // compile-time after unroll
      if (k >= 0 && k < KW) {
        acc[u].x = fmaf(g[k], xj.x, acc[u].x);
        acc[u].y = fmaf(g[k], xj.y, acc[u].y);
        acc[u].z = fmaf(g[k], xj.z, acc[u].z);
        acc[u].w = fmaf(g[k], xj.w, acc[u].w);
      }
    }
  }

  float nfull = 0.f;
#pragma unroll
  for (int k = 0; k < KW; ++k) nfull += g[k];

#pragma unroll
  for (int u = 0; u < TS; ++u) {
    const int t = t0 + u;
    float nt = nfull;
    if (t < KW - 1) {                         // exact partial-sum norm for small t
      nt = 0.f;
#pragma unroll
      for (int k = 0; k < KW; ++k) nt += (k <= t) ? g[k] : 0.f;
    }
    const float inv = 1.0f / nt;
    ushort4 o;
    o.x = f2bf(acc[u].x * inv); o.y = f2bf(acc[u].y * inv);
    o.z = f2bf(acc[u].z * inv); o.w = f2bf(acc[u].w * inv);
    *(ushort4*)(fb + (rb + t) * 1024 + d4 * 4) = o;
  }
}

// ---------------------------------------------------------------------------
// Kernel 2: transpose + bf16-convert the three DxD weight matrices:
// Wt[n][k] = (bf16) W[k][n], so MFMA B-fragments read 16B contiguous along K.
// Grid: dim3(16,16,3), 256 threads, 64x64 tiles via LDS (pad +1 vs conflicts).
// ---------------------------------------------------------------------------
__global__ __launch_bounds__(256) void wconv(
    const float* __restrict__ Wa, const float* __restrict__ Wsh,
    const float* __restrict__ Wsc,
    unsigned short* __restrict__ Oa, unsigned short* __restrict__ Osh,
    unsigned short* __restrict__ Osc)
{
  const float* W; unsigned short* O;
  if (blockIdx.z == 0)      { W = Wa;  O = Oa; }
  else if (blockIdx.z == 1) { W = Wsh; O = Osh; }
  else                      { W = Wsc; O = Osc; }
  const int k0 = blockIdx.x * 64;
  const int n0 = blockIdx.y * 64;
  __shared__ float t[64][65];
  const int r = threadIdx.x >> 4;    // 0..15
  const int c4 = threadIdx.x & 15;   // 0..15
#pragma unroll
  for (int i = 0; i < 4; ++i) {
    const int row = r + i * 16;
    const float4 v = *(const float4*)(W + (size_t)(k0 + row) * 1024 + n0 + c4 * 4);
    t[row][c4 * 4 + 0] = v.x; t[row][c4 * 4 + 1] = v.y;
    t[row][c4 * 4 + 2] = v.z; t[row][c4 * 4 + 3] = v.w;
  }
  __syncthreads();
#pragma unroll
  for (int i = 0; i < 4; ++i) {
    const int nr = r + i * 16;
    ushort4 o;
    o.x = f2bf(t[c4 * 4 + 0][nr]);
    o.y = f2bf(t[c4 * 4 + 1][nr]);
    o.z = f2bf(t[c4 * 4 + 2][nr]);
    o.w = f2bf(t[c4 * 4 + 3][nr]);
    *(ushort4*)(O + (size_t)(n0 + nr) * 1024 + k0 + c4 * 4) = o;
  }
}

// ---------------------------------------------------------------------------
// Kernel 3: fused triple GEMM + epilogue.
//   affine = relu(x@Wa + ba); shift = f@Wsh + bsh; scale = f@Wsc + bsc
//   out = scale*affine + shift
// BM=128 BN=128 BK=64, 512 thr (8 waves, 2Mx4N, 64x32 per wave).
// F/Wa/Wsh/Wsc tiles staged with global_load_lds width=16 (pre-swizzled
// global source, rule #21). X tile reg-staged from f32 x: coalesced float4
// loads -> in-reg RNE bf16 convert -> swizzled ds_write_b64 (same XOR map).
// ---------------------------------------------------------------------------
__global__ __launch_bounds__(512, 2) void fused_gemm(
    const float* __restrict__ x, const unsigned short* __restrict__ Fb,
    const unsigned short* __restrict__ Wta, const unsigned short* __restrict__ Wts,
    const unsigned short* __restrict__ Wtc,
    const float* __restrict__ ba, const float* __restrict__ bsh,
    const float* __restrict__ bsc, float* __restrict__ out)
{
  __shared__ unsigned short sX[128 * 64];
  __shared__ unsigned short sF[128 * 64];
  __shared__ unsigned short sA[128 * 64];
  __shared__ unsigned short sS[128 * 64];
  __shared__ unsigned short sC[128 * 64];

  const int tid = threadIdx.x;
  const int lane = tid & 63;
  const int wid = tid >> 6;      // 0..7
  const int wm = wid >> 2;       // 0..1  (M)
  const int wn = wid & 3;        // 0..3  (N)

  const int bid = blockIdx.x;    // 512 blocks
  const int bn0 = (bid & 7) * 128;   // XCD-friendly: each XCD owns one N column
  const int bm0 = (bid >> 3) * 128;

  // staging map (global_load_lds): physical LDS 16B slot -> (row,col) of tile
  int rowS[2], colS[2];
#pragma unroll
  for (int p = 0; p < 2; ++p) {
    const int po = (p * 512 + tid) * 16;
    const int r = po >> 7;                    // 128B per logical row (64 bf16)
    const int lo = po ^ ((r & 7) << 4);
    rowS[p] = r;
    colS[p] = (lo & 127) >> 1;
  }

  // X reg-staging map: round i covers rows [i*32, i*32+32); within a round
  // thread -> row = i*32 + (tid>>4), f32 col = (tid&15)*4. Lanes 0..15 cover
  // one row contiguously (256B) -> fully coalesced 1KiB/wave per instr.
  const int xr0 = tid >> 4;          // 0..31
  const int xc  = (tid & 15) * 4;    // f32 col
  const int xsw = (xr0 & 7) << 4;    // swizzle XOR, invariant across rounds

  const int lr = lane & 15;      // fragment row/col
  const int lk = lane >> 4;      // k sub-block

  f32x4 accA[4][2], accS[4][2], accC[4][2];
  const f32x4 z = {0.f, 0.f, 0.f, 0.f};
#pragma unroll
  for (int m = 0; m < 4; ++m)
#pragma unroll
    for (int j = 0; j < 2; ++j) { accA[m][j] = z; accS[m][j] = z; accC[m][j] = z; }

  for (int kt = 0; kt < 16; ++kt) {
    const int k0 = kt * 64;
    __syncthreads();   // everyone done reading the previous tile

    // X: issue the 4 coalesced f32 loads first (longest latency)
    float4 xv[4];
#pragma unroll
    for (int i = 0; i < 4; ++i)
      xv[i] = *(const float4*)(x + (size_t)(bm0 + i * 32 + xr0) * 1024 + k0 + xc);

    auto stage = [&](const unsigned short* gsrc, unsigned short* sdst, int rb0) {
#pragma unroll
      for (int p = 0; p < 2; ++p) {
        const unsigned short* src =
            gsrc + (size_t)(rb0 + rowS[p]) * 1024 + k0 + colS[p];
        __builtin_amdgcn_global_load_lds(
            (const __attribute__((address_space(1))) void*)src,
            (__attribute__((address_space(3))) void*)(sdst + (p * 512 + (wid << 6)) * 8),
            16, 0, 0);
      }
    };
    stage(Fb, sF, bm0);
    stage(Wta, sA, bn0);
    stage(Wts, sS, bn0);
    stage(Wtc, sC, bn0);

    // X: convert + swizzled LDS write (same XOR map as the read side)
#pragma unroll
    for (int i = 0; i < 4; ++i) {
      ushort4 o;
      o.x = f2bf(xv[i].x); o.y = f2bf(xv[i].y);
      o.z = f2bf(xv[i].z); o.w = f2bf(xv[i].w);
      const int row = i * 32 + xr0;
      const int po = (row * 128 + xc * 2) ^ xsw;
      *(ushort4*)((char*)sX + po) = o;
    }

    __syncthreads();   // compiler drains vmcnt(0) + lgkmcnt(0) here

#pragma unroll
    for (int s = 0; s < 2; ++s) {
      bf16x8 ax[4], af[4], bA[2], bS[2], bC[2];
#pragma unroll
      for (int m = 0; m < 4; ++m) {
        const int row = wm * 64 + m * 16 + lr;
        const int po = (row * 128 + (s * 32 + lk * 8) * 2) ^ ((row & 7) << 4);
        ax[m] = *(const bf16x8*)((const char*)sX + po);
        af[m] = *(const bf16x8*)((const char*)sF + po);
      }
#pragma unroll
      for (int j = 0; j < 2; ++j) {
        const int row = wn * 32 + j * 16 + lr;
        const int po = (row * 128 + (s * 32 + lk * 8) * 2) ^ ((row & 7) << 4);
        bA[j] = *(const bf16x8*)((const char*)sA + po);
        bS[j] = *(const bf16x8*)((const char*)sS + po);
        bC[j] = *(const bf16x8*)((const char*)sC + po);
      }
#pragma unroll
      for (int m = 0; m < 4; ++m)
#pragma unroll
        for (int j = 0; j < 2; ++j) {
          accA[m][j] = __builtin_amdgcn_mfma_f32_16x16x32_bf16(ax[m], bA[j], accA[m][j], 0, 0, 0);
          accS[m][j] = __builtin_amdgcn_mfma_f32_16x16x32_bf16(af[m], bS[j], accS[m][j], 0, 0, 0);
          accC[m][j] = __builtin_amdgcn_mfma_f32_16x16x32_bf16(af[m], bC[j], accC[m][j], 0, 0, 0);
        }
    }
  }

  // epilogue: bias + relu + combine, f32 out. C/D layout: col=lane&15,
  // row=(lane>>4)*4+reg  [measured m89/m91]
#pragma unroll
  for (int j = 0; j < 2; ++j) {
    const int n = bn0 + wn * 32 + j * 16 + lr;
    const float Ba = ba[n], Bs = bsh[n], Bc = bsc[n];
#pragma unroll
    for (int m = 0; m < 4; ++m) {
      const int rbase = bm0 + wm * 64 + m * 16 + lk * 4;
#pragma unroll
      for (int r = 0; r < 4; ++r) {
        float aff = accA[m][j][r] + Ba;
        aff = fmaxf(aff, 0.0f);
        const float v = (accC[m][j][r] + Bc) * aff + (accS[m][j][r] + Bs);
        out[(size_t)(rbase + r) * 1024 + n] = v;
      }
    }
  }
}

// ---------------------------------------------------------------------------
// Workspace layout (22 MiB total -- must stay under ws_size; the R1 failure
// was a 38 MiB layout overflowing d_ws and corrupting an input buffer):
//   Fb  : ws + 0        16 MiB  (filtered, bf16)
//   Wta : ws + 16 MiB    2 MiB  (Wa^T, bf16)
//   Wts : ws + 18 MiB    2 MiB  (Wshift^T, bf16)
//   Wtc : ws + 20 MiB    2 MiB  (Wscale^T, bf16)
// ---------------------------------------------------------------------------
extern "C" void kernel_launch(void* const* d_in, const int* in_sizes, int n_in,
                              void* d_out, int out_size, void* d_ws, size_t ws_size,
                              hipStream_t stream) {
  const float* x   = (const float*)d_in[0];
  const float* Wa  = (const float*)d_in[1];
  const float* ba  = (const float*)d_in[2];
  const float* Wsh = (const float*)d_in[3];
  const float* bsh = (const float*)d_in[4];
  const float* Wsc = (const float*)d_in[5];
  const float* bsc = (const float*)d_in[6];
  float* out = (float*)d_out;

  char* ws = (char*)d_ws;
  unsigned short* Fb  = (unsigned short*)(ws);
  unsigned short* Wta = (unsigned short*)(ws + (16u << 20));
  unsigned short* Wts = (unsigned short*)(ws + (18u << 20));
  unsigned short* Wtc = (unsigned short*)(ws + (20u << 20));

  hipLaunchKernelGGL(filter_conv, dim3(1024), dim3(256), 0, stream, x, Fb);
  hipLaunchKernelGGL(wconv, dim3(16, 16, 3), dim3(256), 0, stream,
                     Wa, Wsh, Wsc, Wta, Wts, Wtc);
  hipLaunchKernelGGL(fused_gemm, dim3(512), dim3(512), 0, stream,
                     x, Fb, Wta, Wts, Wtc, ba, bsh, bsc, out);
}